// Round 1
// baseline (2625.804 us; speedup 1.0000x reference)
//
#include <hip/hip_runtime.h>
#include <cstdint>
#include <math.h>

#define T_SEQ 2048
#define BATCH 2
#define NH 16
#define NKV 4
#define HD 128

// ---------------------------------------------------------------------------
// fp32 tiled GEMM: C[M,N] = A[M,K] @ B[K,N], all row-major.
// 64x64 block tile, BK=16, 256 threads, 4x4 microtile per thread.
// Assumes M%64==0, N%64==0, K%16==0 (true for all shapes here).
// ---------------------------------------------------------------------------
__global__ __launch_bounds__(256) void gemm_f32(
    const float* __restrict__ A, const float* __restrict__ B,
    float* __restrict__ C, int M, int N, int K) {
  __shared__ float As[16][68];  // As[k][m], pad 68 keeps float4 reads aligned
  __shared__ float Bs[16][68];  // Bs[k][n]
  const int tid = threadIdx.x;
  const int tx = tid & 15, ty = tid >> 4;
  const int bm = blockIdx.y * 64, bn = blockIdx.x * 64;
  const int arow = tid >> 2, ak = (tid & 3) << 2;
  const int brow = tid >> 4, bcol = (tid & 15) << 2;
  float acc[4][4] = {};
  const float* Ap = A + (size_t)(bm + arow) * K + ak;
  const float* Bp = B + (size_t)brow * N + (bn + bcol);
  for (int k0 = 0; k0 < K; k0 += 16) {
    float4 av = *(const float4*)(Ap + k0);
    float4 bv = *(const float4*)(Bp + (size_t)k0 * N);
    As[ak + 0][arow] = av.x;
    As[ak + 1][arow] = av.y;
    As[ak + 2][arow] = av.z;
    As[ak + 3][arow] = av.w;
    *(float4*)&Bs[brow][bcol] = bv;
    __syncthreads();
#pragma unroll
    for (int k = 0; k < 16; ++k) {
      float4 a = *(const float4*)&As[k][ty << 2];
      float4 b = *(const float4*)&Bs[k][tx << 2];
      acc[0][0] += a.x * b.x; acc[0][1] += a.x * b.y; acc[0][2] += a.x * b.z; acc[0][3] += a.x * b.w;
      acc[1][0] += a.y * b.x; acc[1][1] += a.y * b.y; acc[1][2] += a.y * b.z; acc[1][3] += a.y * b.w;
      acc[2][0] += a.z * b.x; acc[2][1] += a.z * b.y; acc[2][2] += a.z * b.z; acc[2][3] += a.z * b.w;
      acc[3][0] += a.w * b.x; acc[3][1] += a.w * b.y; acc[3][2] += a.w * b.z; acc[3][3] += a.w * b.w;
    }
    __syncthreads();
  }
#pragma unroll
  for (int r = 0; r < 4; ++r) {
    float4 cv = make_float4(acc[r][0], acc[r][1], acc[r][2], acc[r][3]);
    *(float4*)&C[(size_t)(bm + (ty << 2) + r) * N + bn + (tx << 2)] = cv;
  }
}

// ---------------------------------------------------------------------------
// Interleaved RoPE applied in-place to q (B*T, NH*HD) and k (B*T, NKV*HD).
// out[2i]   = x[2i]*cos - x[2i+1]*sin
// out[2i+1] = x[2i]*sin + x[2i+1]*cos,  angle = t * 10000^(-i/64)
// ---------------------------------------------------------------------------
__global__ __launch_bounds__(256) void rope_kernel(float* __restrict__ q,
                                                   float* __restrict__ k) {
  const int QP = BATCH * T_SEQ * NH * 64;
  const int KP = BATCH * T_SEQ * NKV * 64;
  int idx = blockIdx.x * 256 + threadIdx.x;
  float* p;
  int i, t;
  if (idx < QP) {
    i = idx & 63;
    int h = (idx >> 6) & (NH - 1);
    int row = idx >> 10;  // /(NH*64)
    t = row & (T_SEQ - 1);
    p = q + (size_t)row * (NH * HD) + h * HD + 2 * i;
  } else if (idx < QP + KP) {
    int j = idx - QP;
    i = j & 63;
    int h = (j >> 6) & (NKV - 1);
    int row = j >> 8;  // /(NKV*64)
    t = row & (T_SEQ - 1);
    p = k + (size_t)row * (NKV * HD) + h * HD + 2 * i;
  } else {
    return;
  }
  // inv_freq = 10000^(-i/64) = exp(-i * ln(10000)/64)
  float inv = expf((float)i * -0.14391156831212788f);
  float ang = (float)t * inv;
  float sn, cs;
  sincosf(ang, &sn, &cs);
  float x1 = p[0], x2 = p[1];
  p[0] = x1 * cs - x2 * sn;
  p[1] = x1 * sn + x2 * cs;
}

// ---------------------------------------------------------------------------
// Flash-style causal GQA attention, fp32.
// grid: (T/64, NH, B); block 256 (16 tx x 16 ty).
// Each block: 64 query rows, streams K/V in 32-row tiles.
// Per-thread: 4 q-rows (ty*4+r) x 2 keys (tx*2+c) score microtile;
//             O accum 4 rows x 8 cols (d = tx*4+c and 64+tx*4+c).
// Online softmax state in registers, replicated across tx via shfl_xor.
// LDS (exactly 64 KB): Qs[d][m] 32K, KsPs 16K (K tile, aliased by P^T), Vs 16K.
// ---------------------------------------------------------------------------
__global__ __launch_bounds__(256) void attn_f32(
    const float* __restrict__ q, const float* __restrict__ k,
    const float* __restrict__ v, float* __restrict__ out) {
  __shared__ float Qs[128][64];     // [d][m]
  __shared__ float KsPs[128 * 32];  // Ks: [d][32] xor-swizzled; alias Ps: [j][68]
  __shared__ float Vs[32][128];     // [n][d]
  const int tid = threadIdx.x;
  const int tx = tid & 15, ty = tid >> 4;
  const int qt0 = blockIdx.x * 64;
  const int h = blockIdx.y;
  const int b = blockIdx.z;
  const int kvh = h >> 2;
  const float scale = 0.08838834764831845f;  // 1/sqrt(128)

  // Load Q tile -> Qs[d][m] (transposed scatter; one-time cost)
  for (int it = 0; it < 8; ++it) {
    int idx = tid + it * 256;
    int m = idx >> 5;
    int d4 = (idx & 31) << 2;
    float4 qv = *(const float4*)&q[((size_t)(b * T_SEQ + qt0 + m)) * (NH * HD) + h * HD + d4];
    Qs[d4 + 0][m] = qv.x;
    Qs[d4 + 1][m] = qv.y;
    Qs[d4 + 2][m] = qv.z;
    Qs[d4 + 3][m] = qv.w;
  }

  float o[4][8] = {};
  float m_i[4], l_i[4];
#pragma unroll
  for (int r = 0; r < 4; ++r) { m_i[r] = -1e30f; l_i[r] = 0.0f; }

  const int nkt = (qt0 >> 5) + 2;  // causal: keys up to qt0+63
  for (int kt = 0; kt < nkt; ++kt) {
    const int kt0 = kt << 5;
    __syncthreads();  // previous tile's P.V reads done before overwrite
    // Load K (xor-swizzled transpose) and V tiles
    for (int it = 0; it < 4; ++it) {
      int idx = tid + it * 256;
      int n = idx >> 5;
      int d4 = (idx & 31) << 2;
      size_t base = ((size_t)(b * T_SEQ + kt0 + n)) * (NKV * HD) + kvh * HD + d4;
      float4 kv4 = *(const float4*)&k[base];
      KsPs[(d4 + 0) * 32 + (n ^ ((d4 + 0) & 30))] = kv4.x;
      KsPs[(d4 + 1) * 32 + (n ^ ((d4 + 1) & 30))] = kv4.y;
      KsPs[(d4 + 2) * 32 + (n ^ ((d4 + 2) & 30))] = kv4.z;
      KsPs[(d4 + 3) * 32 + (n ^ ((d4 + 3) & 30))] = kv4.w;
      float4 vv = *(const float4*)&v[base];
      *(float4*)&Vs[n][d4] = vv;
    }
    __syncthreads();

    // S microtile = Q K^T
    float s[4][2] = {};
#pragma unroll 4
    for (int dd = 0; dd < 128; ++dd) {
      float4 a = *(const float4*)&Qs[dd][ty << 2];
      float2 kk2 = *(const float2*)&KsPs[dd * 32 + (((tx << 1)) ^ (dd & 30))];
      s[0][0] += a.x * kk2.x; s[0][1] += a.x * kk2.y;
      s[1][0] += a.y * kk2.x; s[1][1] += a.y * kk2.y;
      s[2][0] += a.z * kk2.x; s[2][1] += a.z * kk2.y;
      s[3][0] += a.w * kk2.x; s[3][1] += a.w * kk2.y;
    }
    // scale + causal mask
#pragma unroll
    for (int r = 0; r < 4; ++r) {
      int qi = qt0 + (ty << 2) + r;
#pragma unroll
      for (int c = 0; c < 2; ++c) {
        int ki = kt0 + (tx << 1) + c;
        s[r][c] = (ki <= qi) ? s[r][c] * scale : -1e30f;
      }
    }
    // Online softmax: row state replicated across the 16 tx lanes
    float p[4][2];
#pragma unroll
    for (int r = 0; r < 4; ++r) {
      float rm = fmaxf(s[r][0], s[r][1]);
      rm = fmaxf(rm, __shfl_xor(rm, 1));
      rm = fmaxf(rm, __shfl_xor(rm, 2));
      rm = fmaxf(rm, __shfl_xor(rm, 4));
      rm = fmaxf(rm, __shfl_xor(rm, 8));
      float mnew = fmaxf(m_i[r], rm);
      float alpha = expf(m_i[r] - mnew);
      p[r][0] = expf(s[r][0] - mnew);
      p[r][1] = expf(s[r][1] - mnew);
      float ts = p[r][0] + p[r][1];
      ts += __shfl_xor(ts, 1);
      ts += __shfl_xor(ts, 2);
      ts += __shfl_xor(ts, 4);
      ts += __shfl_xor(ts, 8);
      l_i[r] = l_i[r] * alpha + ts;
      m_i[r] = mnew;
#pragma unroll
      for (int c = 0; c < 8; ++c) o[r][c] *= alpha;
    }
    __syncthreads();  // all K reads done before P^T overwrites the K buffer
    // Store P^T into the (dead) K region: Ps[j][m], stride 68
#pragma unroll
    for (int r = 0; r < 4; ++r) {
      KsPs[((tx << 1) + 0) * 68 + (ty << 2) + r] = p[r][0];
      KsPs[((tx << 1) + 1) * 68 + (ty << 2) + r] = p[r][1];
    }
    __syncthreads();
    // O += P V
#pragma unroll 4
    for (int j = 0; j < 32; ++j) {
      float4 pr = *(const float4*)&KsPs[j * 68 + (ty << 2)];
      float4 va = *(const float4*)&Vs[j][tx << 2];
      float4 vb = *(const float4*)&Vs[j][64 + (tx << 2)];
      o[0][0] += pr.x * va.x; o[0][1] += pr.x * va.y; o[0][2] += pr.x * va.z; o[0][3] += pr.x * va.w;
      o[0][4] += pr.x * vb.x; o[0][5] += pr.x * vb.y; o[0][6] += pr.x * vb.z; o[0][7] += pr.x * vb.w;
      o[1][0] += pr.y * va.x; o[1][1] += pr.y * va.y; o[1][2] += pr.y * va.z; o[1][3] += pr.y * va.w;
      o[1][4] += pr.y * vb.x; o[1][5] += pr.y * vb.y; o[1][6] += pr.y * vb.z; o[1][7] += pr.y * vb.w;
      o[2][0] += pr.z * va.x; o[2][1] += pr.z * va.y; o[2][2] += pr.z * va.z; o[2][3] += pr.z * va.w;
      o[2][4] += pr.z * vb.x; o[2][5] += pr.z * vb.y; o[2][6] += pr.z * vb.z; o[2][7] += pr.z * vb.w;
      o[3][0] += pr.w * va.x; o[3][1] += pr.w * va.y; o[3][2] += pr.w * va.z; o[3][3] += pr.w * va.w;
      o[3][4] += pr.w * vb.x; o[3][5] += pr.w * vb.y; o[3][6] += pr.w * vb.z; o[3][7] += pr.w * vb.w;
    }
  }
  // Epilogue: normalize and write (B, T, NH*HD)
#pragma unroll
  for (int r = 0; r < 4; ++r) {
    float inv = 1.0f / l_i[r];
    size_t base = ((size_t)(b * T_SEQ + qt0 + (ty << 2) + r)) * (NH * HD) + h * HD;
    float4 oa = make_float4(o[r][0] * inv, o[r][1] * inv, o[r][2] * inv, o[r][3] * inv);
    float4 ob = make_float4(o[r][4] * inv, o[r][5] * inv, o[r][6] * inv, o[r][7] * inv);
    *(float4*)&out[base + (tx << 2)] = oa;
    *(float4*)&out[base + 64 + (tx << 2)] = ob;
  }
}

// ---------------------------------------------------------------------------
extern "C" void kernel_launch(void* const* d_in, const int* in_sizes, int n_in,
                              void* d_out, int out_size, void* d_ws, size_t ws_size,
                              hipStream_t stream) {
  const float* x  = (const float*)d_in[0];
  const float* Wq = (const float*)d_in[1];
  const float* Wk = (const float*)d_in[2];
  const float* Wv = (const float*)d_in[3];
  const float* Wo = (const float*)d_in[4];
  float* y = (float*)d_out;
  float* ws = (float*)d_ws;

  const int M = BATCH * T_SEQ;  // 4096
  float* qb = ws;                                  // 4096*2048 f32 (32 MB)
  float* kb = qb + (size_t)M * NH * HD;            // 4096*512  f32 ( 8 MB)
  float* vb = kb + (size_t)M * NKV * HD;           // 4096*512  f32 ( 8 MB)
  float* ao = vb + (size_t)M * NKV * HD;           // 4096*2048 f32 (32 MB)

  dim3 blk(256);
  gemm_f32<<<dim3((NH * HD) / 64, M / 64), blk, 0, stream>>>(x, Wq, qb, M, NH * HD, 2048);
  gemm_f32<<<dim3((NKV * HD) / 64, M / 64), blk, 0, stream>>>(x, Wk, kb, M, NKV * HD, 2048);
  gemm_f32<<<dim3((NKV * HD) / 64, M / 64), blk, 0, stream>>>(x, Wv, vb, M, NKV * HD, 2048);

  int pairs = M * NH * 64 + M * NKV * 64;
  rope_kernel<<<(pairs + 255) / 256, blk, 0, stream>>>(qb, kb);

  attn_f32<<<dim3(T_SEQ / 64, NH, BATCH), blk, 0, stream>>>(qb, kb, vb, ao);

  gemm_f32<<<dim3(2048 / 64, M / 64), blk, 0, stream>>>(ao, Wo, y, M, 2048, 2048);
}

// Round 2
// 439.075 us; speedup vs baseline: 5.9803x; 5.9803x over previous
//
#include <hip/hip_runtime.h>
#include <cstdint>
#include <math.h>

#define T_SEQ 2048
#define BATCH 2
#define NH 16
#define NKV 4
#define HD 128

typedef __attribute__((ext_vector_type(8))) short short8;
typedef __attribute__((ext_vector_type(4))) float f32x4;

__device__ __forceinline__ ushort f2bf(float f) {
  uint32_t u = __builtin_bit_cast(uint32_t, f);
  u += 0x7FFF + ((u >> 16) & 1);  // RNE
  return (ushort)(u >> 16);
}
__device__ __forceinline__ float bf2f(ushort u) {
  uint32_t v = ((uint32_t)u) << 16;
  return __builtin_bit_cast(float, v);
}
// async 16B/lane global->LDS DMA. lds must be wave-uniform; hw adds lane*16.
__device__ __forceinline__ void ld16(void* lds, const void* g) {
  __builtin_amdgcn_global_load_lds((const __attribute__((address_space(1))) void*)g,
                                   (__attribute__((address_space(3))) void*)lds,
                                   16, 0, 0);
}

// ---------------------------------------------------------------------------
// fp32 -> bf16 elementwise (x)
// ---------------------------------------------------------------------------
__global__ __launch_bounds__(256) void convert_f32_bf16(const float* __restrict__ in,
                                                        ushort* __restrict__ out, int n) {
  int i = (blockIdx.x * 256 + threadIdx.x) * 4;
  if (i >= n) return;
  float4 v = *(const float4*)&in[i];
  ushort4 o;
  o.x = f2bf(v.x); o.y = f2bf(v.y); o.z = f2bf(v.z); o.w = f2bf(v.w);
  *(ushort4*)&out[i] = o;
}

// ---------------------------------------------------------------------------
// fp32 [K][N] -> bf16 [N][K] (weights to B^T layout). grid (N/32, K/32).
// ---------------------------------------------------------------------------
__global__ __launch_bounds__(256) void transpose_f32_bf16(const float* __restrict__ in,
                                                          ushort* __restrict__ out,
                                                          int K, int N) {
  __shared__ float tile[32][33];
  int n0 = blockIdx.x * 32, k0 = blockIdx.y * 32;
  int r = threadIdx.x >> 3, c4 = (threadIdx.x & 7) << 2;
  float4 v = *(const float4*)&in[(size_t)(k0 + r) * N + n0 + c4];
  tile[r][c4 + 0] = v.x; tile[r][c4 + 1] = v.y;
  tile[r][c4 + 2] = v.z; tile[r][c4 + 3] = v.w;
  __syncthreads();
  ushort4 o;
  o.x = f2bf(tile[c4 + 0][r]); o.y = f2bf(tile[c4 + 1][r]);
  o.z = f2bf(tile[c4 + 2][r]); o.w = f2bf(tile[c4 + 3][r]);
  *(ushort4*)&out[(size_t)(n0 + r) * K + k0 + c4] = o;
}

// ---------------------------------------------------------------------------
// bf16 GEMM C[M,N] = A[M,K] * Bt[N,K]^T. 128x128 tile, BK=32, 4 waves (2x2),
// global_load_lds staging with XOR-swizzled LDS ((row>>1)&3 on 16B chunks).
// ---------------------------------------------------------------------------
template <typename OutT>
__global__ __launch_bounds__(256) void gemm_bt(const ushort* __restrict__ A,
                                               const ushort* __restrict__ Bt,
                                               OutT* __restrict__ C,
                                               int M, int N, int K) {
  __shared__ __align__(16) ushort As[128 * 32];
  __shared__ __align__(16) ushort Bs[128 * 32];
  const int tid = threadIdx.x;
  const int w = tid >> 6, l = tid & 63;
  const int wr = w >> 1, wc = w & 1;
  const int quad = l >> 4, l15 = l & 15;
  const int bm = blockIdx.y * 128, bn = blockIdx.x * 128;

  f32x4 acc[4][4];
#pragma unroll
  for (int mi = 0; mi < 4; ++mi)
#pragma unroll
    for (int ni = 0; ni < 4; ++ni)
#pragma unroll
      for (int r = 0; r < 4; ++r) acc[mi][ni][r] = 0.f;

  for (int k0 = 0; k0 < K; k0 += 32) {
    __syncthreads();
#pragma unroll
    for (int j = 0; j < 2; ++j) {
      int r0 = w * 32 + j * 16;
      int row = r0 + (l >> 2);
      int gc = (l & 3) ^ ((row >> 1) & 3);
      ld16(&As[r0 * 32], &A[(size_t)(bm + row) * K + k0 + gc * 8]);
      ld16(&Bs[r0 * 32], &Bt[(size_t)(bn + row) * K + k0 + gc * 8]);
    }
    __syncthreads();
    short8 af[4], bf[4];
#pragma unroll
    for (int mi = 0; mi < 4; ++mi) {
      int m = wr * 64 + mi * 16 + l15;
      af[mi] = *(const short8*)&As[m * 32 + (quad ^ ((m >> 1) & 3)) * 8];
    }
#pragma unroll
    for (int ni = 0; ni < 4; ++ni) {
      int n = wc * 64 + ni * 16 + l15;
      bf[ni] = *(const short8*)&Bs[n * 32 + (quad ^ ((n >> 1) & 3)) * 8];
    }
#pragma unroll
    for (int mi = 0; mi < 4; ++mi)
#pragma unroll
      for (int ni = 0; ni < 4; ++ni)
        acc[mi][ni] = __builtin_amdgcn_mfma_f32_16x16x32_bf16(af[mi], bf[ni], acc[mi][ni], 0, 0, 0);
  }
  // epilogue: C/D layout col=lane&15, row=quad*4+reg
#pragma unroll
  for (int mi = 0; mi < 4; ++mi)
#pragma unroll
    for (int ni = 0; ni < 4; ++ni)
#pragma unroll
      for (int r = 0; r < 4; ++r) {
        int grow = bm + wr * 64 + mi * 16 + quad * 4 + r;
        int gcol = bn + wc * 64 + ni * 16 + l15;
        if constexpr (__is_same(OutT, ushort))
          C[(size_t)grow * N + gcol] = f2bf(acc[mi][ni][r]);
        else
          C[(size_t)grow * N + gcol] = acc[mi][ni][r];
      }
}

// ---------------------------------------------------------------------------
// RoPE in-place on bf16 qkv [4096][3072]: q cols 0..2047, k cols 2048..2559.
// ---------------------------------------------------------------------------
__global__ __launch_bounds__(256) void rope_bf16(ushort* __restrict__ qkv) {
  int idx = blockIdx.x * 256 + threadIdx.x;
  const int PAIRS_PER_ROW = 1280;  // 1024 q pairs + 256 k pairs
  if (idx >= BATCH * T_SEQ * PAIRS_PER_ROW) return;
  int row = idx / PAIRS_PER_ROW;
  int p = idx - row * PAIRS_PER_ROW;
  int t = row & (T_SEQ - 1);
  int col, i;
  if (p < 1024) { i = p & 63; col = 2 * p; }
  else { int kp = p - 1024; i = kp & 63; col = 2048 + 2 * kp; }
  ushort* ptr = qkv + (size_t)row * 3072 + col;
  float inv = expf((float)i * -0.14391156831212788f);  // ln(10000)/64
  float ang = (float)t * inv;
  float sn, cs;
  sincosf(ang, &sn, &cs);
  float x1 = bf2f(ptr[0]), x2 = bf2f(ptr[1]);
  ptr[0] = f2bf(x1 * cs - x2 * sn);
  ptr[1] = f2bf(x1 * sn + x2 * cs);
}

// ---------------------------------------------------------------------------
// v columns of qkv [4096][3072] (cols 2560..3071) -> vT [512][4096] bf16.
// grid (4096/32, 512/32).
// ---------------------------------------------------------------------------
__global__ __launch_bounds__(256) void transpose_v(const ushort* __restrict__ qkv,
                                                   ushort* __restrict__ vT) {
  __shared__ ushort tile[32][34];
  int m0 = blockIdx.x * 32, d0 = blockIdx.y * 32;
  int r = threadIdx.x >> 3, c4 = (threadIdx.x & 7) << 2;
  ushort4 v = *(const ushort4*)&qkv[(size_t)(m0 + r) * 3072 + 2560 + d0 + c4];
  tile[r][c4 + 0] = v.x; tile[r][c4 + 1] = v.y;
  tile[r][c4 + 2] = v.z; tile[r][c4 + 3] = v.w;
  __syncthreads();
  ushort4 o;
  o.x = tile[c4 + 0][r]; o.y = tile[c4 + 1][r];
  o.z = tile[c4 + 2][r]; o.w = tile[c4 + 3][r];
  *(ushort4*)&vT[(size_t)(d0 + r) * 4096 + m0 + c4] = o;
}

// ---------------------------------------------------------------------------
// MFMA flash attention. grid (T/64, NH, B), 256 thr = 4 waves.
// Wave w owns S/O rows w*16..w*16+15 of the 64-row Q tile.
// LDS 56KB: Qs/Ks [64][128] bf16 swizzle (row>>1)&7; Vt [128][64] swizzle d&7;
// Ps per-wave [16][64] swizzle row&7 (P C-layout -> A-layout round trip).
// ---------------------------------------------------------------------------
__global__ __launch_bounds__(256) void attn_mfma(const ushort* __restrict__ qkv,
                                                 const ushort* __restrict__ vT,
                                                 ushort* __restrict__ ao) {
  __shared__ __align__(16) ushort Qs[64 * 128];
  __shared__ __align__(16) ushort Ks[64 * 128];
  __shared__ __align__(16) ushort Vt[128 * 64];
  __shared__ __align__(16) ushort Ps[4][16 * 64];
  const int tid = threadIdx.x;
  const int w = tid >> 6, l = tid & 63;
  const int quad = l >> 4, l15 = l & 15;
  const int qt0 = blockIdx.x * 64;
  const int h = blockIdx.y, b = blockIdx.z;
  const int kvh = h >> 2;
  const size_t qrow0 = (size_t)b * T_SEQ + qt0;
  const float SC = 0.12751744595764253f;  // (1/sqrt(128)) * log2(e)

  // stage Q tile (swizzled)
#pragma unroll
  for (int j = 0; j < 4; ++j) {
    int r0 = w * 16 + j * 4;
    int row = r0 + (l >> 4);
    int gc = (l & 15) ^ ((row >> 1) & 7);
    ld16(&Qs[r0 * 128], &qkv[(qrow0 + row) * 3072 + h * 128 + gc * 8]);
  }

  f32x4 oacc[8];
#pragma unroll
  for (int i = 0; i < 8; ++i)
#pragma unroll
    for (int r = 0; r < 4; ++r) oacc[i][r] = 0.f;
  float m_i[4], l_i[4];
#pragma unroll
  for (int r = 0; r < 4; ++r) { m_i[r] = -1e30f; l_i[r] = 0.f; }

  const int nkt = (qt0 >> 6) + 1;
  for (int kt = 0; kt < nkt; ++kt) {
    const int kt0 = kt << 6;
    __syncthreads();  // prior iter's K/V reads complete
#pragma unroll
    for (int j = 0; j < 4; ++j) {  // stage K tile
      int r0 = w * 16 + j * 4;
      int row = r0 + (l >> 4);
      int gc = (l & 15) ^ ((row >> 1) & 7);
      ld16(&Ks[r0 * 128], &qkv[((size_t)b * T_SEQ + kt0 + row) * 3072 + 2048 + kvh * 128 + gc * 8]);
    }
#pragma unroll
    for (int j = 0; j < 4; ++j) {  // stage V^T tile
      int r0 = w * 32 + j * 8;
      int row = r0 + (l >> 3);
      int gc = (l & 7) ^ (row & 7);
      ld16(&Vt[r0 * 64], &vT[(size_t)(kvh * 128 + row) * 4096 + (size_t)b * T_SEQ + kt0 + gc * 8]);
    }
    __syncthreads();  // staging complete (vmcnt drained before barrier)

    // S = Q K^T (rows w*16.., cols 0..63)
    f32x4 sacc[4];
#pragma unroll
    for (int ni = 0; ni < 4; ++ni)
#pragma unroll
      for (int r = 0; r < 4; ++r) sacc[ni][r] = 0.f;
#pragma unroll
    for (int kc = 0; kc < 4; ++kc) {
      int m = w * 16 + l15;
      short8 a = *(const short8*)&Qs[m * 128 + ((kc * 4 + quad) ^ ((m >> 1) & 7)) * 8];
#pragma unroll
      for (int ni = 0; ni < 4; ++ni) {
        int n = ni * 16 + l15;
        short8 bfr = *(const short8*)&Ks[n * 128 + ((kc * 4 + quad) ^ ((n >> 1) & 7)) * 8];
        sacc[ni] = __builtin_amdgcn_mfma_f32_16x16x32_bf16(a, bfr, sacc[ni], 0, 0, 0);
      }
    }

    const bool diag = (kt == nkt - 1);
    float p[4][4];
#pragma unroll
    for (int r = 0; r < 4; ++r) {
      int qi = qt0 + w * 16 + quad * 4 + r;
      float sv[4];
      float rm = -1e30f;
#pragma unroll
      for (int ni = 0; ni < 4; ++ni) {
        float s = sacc[ni][r] * SC;  // base-2 units
        if (diag && (kt0 + ni * 16 + l15) > qi) s = -1e30f;
        sv[ni] = s;
        rm = fmaxf(rm, s);
      }
      rm = fmaxf(rm, __shfl_xor(rm, 1));
      rm = fmaxf(rm, __shfl_xor(rm, 2));
      rm = fmaxf(rm, __shfl_xor(rm, 4));
      rm = fmaxf(rm, __shfl_xor(rm, 8));
      float mnew = fmaxf(m_i[r], rm);
      float alpha = exp2f(m_i[r] - mnew);
      float ts = 0.f;
#pragma unroll
      for (int ni = 0; ni < 4; ++ni) { p[ni][r] = exp2f(sv[ni] - mnew); ts += p[ni][r]; }
      ts += __shfl_xor(ts, 1);
      ts += __shfl_xor(ts, 2);
      ts += __shfl_xor(ts, 4);
      ts += __shfl_xor(ts, 8);
      l_i[r] = l_i[r] * alpha + ts;
      m_i[r] = mnew;
#pragma unroll
      for (int ni2 = 0; ni2 < 8; ++ni2) oacc[ni2][r] *= alpha;
    }

    // P (C-layout regs) -> Ps[w] (A-layout source), bf16, swizzled
    ushort* pw = Ps[w];
#pragma unroll
    for (int ni = 0; ni < 4; ++ni) {
      int colc = ni * 2 + (l15 >> 3);
      int within = l & 7;
#pragma unroll
      for (int r = 0; r < 4; ++r) {
        int prow = quad * 4 + r;
        pw[prow * 64 + ((colc ^ (prow & 7)) << 3) + within] = f2bf(p[ni][r]);
      }
    }
    // O += P V  (A = Ps rows m=l&15, B = Vt rows d)
#pragma unroll
    for (int kc = 0; kc < 2; ++kc) {
      short8 a = *(const short8*)&pw[l15 * 64 + ((kc * 4 + quad) ^ (l15 & 7)) * 8];
#pragma unroll
      for (int ni2 = 0; ni2 < 8; ++ni2) {
        int d = ni2 * 16 + l15;
        short8 bfr = *(const short8*)&Vt[d * 64 + ((kc * 4 + quad) ^ (d & 7)) * 8];
        oacc[ni2] = __builtin_amdgcn_mfma_f32_16x16x32_bf16(a, bfr, oacc[ni2], 0, 0, 0);
      }
    }
  }
  // epilogue
#pragma unroll
  for (int r = 0; r < 4; ++r) {
    float inv = 1.f / l_i[r];
    size_t grow = qrow0 + w * 16 + quad * 4 + r;
#pragma unroll
    for (int ni2 = 0; ni2 < 8; ++ni2)
      ao[grow * 2048 + h * 128 + ni2 * 16 + l15] = f2bf(oacc[ni2][r] * inv);
  }
}

// ---------------------------------------------------------------------------
extern "C" void kernel_launch(void* const* d_in, const int* in_sizes, int n_in,
                              void* d_out, int out_size, void* d_ws, size_t ws_size,
                              hipStream_t stream) {
  const float* x  = (const float*)d_in[0];
  const float* Wq = (const float*)d_in[1];
  const float* Wk = (const float*)d_in[2];
  const float* Wv = (const float*)d_in[3];
  const float* Wo = (const float*)d_in[4];
  float* y = (float*)d_out;

  const int M = BATCH * T_SEQ;  // 4096
  ushort* xb    = (ushort*)d_ws;                    // 4096*2048  (16 MB)
  ushort* wqkvT = xb + (size_t)M * 2048;            // 3072*2048  (12 MB)
  ushort* woT   = wqkvT + (size_t)3072 * 2048;      // 2048*2048  ( 8 MB)
  ushort* qkv   = woT + (size_t)2048 * 2048;        // 4096*3072  (24 MB)
  ushort* vTb   = qkv + (size_t)M * 3072;           // 512*4096   ( 4 MB)
  ushort* aob   = vTb + (size_t)512 * 4096;         // 4096*2048  (16 MB)

  dim3 blk(256);
  convert_f32_bf16<<<(M * 2048 / 4 + 255) / 256, blk, 0, stream>>>(x, xb, M * 2048);
  transpose_f32_bf16<<<dim3(64, 64), blk, 0, stream>>>(Wq, wqkvT, 2048, 2048);
  transpose_f32_bf16<<<dim3(16, 64), blk, 0, stream>>>(Wk, wqkvT + (size_t)2048 * 2048, 2048, 512);
  transpose_f32_bf16<<<dim3(16, 64), blk, 0, stream>>>(Wv, wqkvT + (size_t)2560 * 2048, 2048, 512);
  transpose_f32_bf16<<<dim3(64, 64), blk, 0, stream>>>(Wo, woT, 2048, 2048);

  gemm_bt<ushort><<<dim3(3072 / 128, M / 128), blk, 0, stream>>>(xb, wqkvT, qkv, M, 3072, 2048);

  rope_bf16<<<(M * 1280 + 255) / 256, blk, 0, stream>>>(qkv);
  transpose_v<<<dim3(M / 32, 512 / 32), blk, 0, stream>>>(qkv, vTb);

  attn_mfma<<<dim3(T_SEQ / 64, NH, BATCH), blk, 0, stream>>>(qkv, vTb, aob);

  gemm_bt<float><<<dim3(2048 / 128, M / 128), blk, 0, stream>>>(aob, woT, y, M, 2048, 2048);
}